// Round 14
// baseline (267.391 us; speedup 1.0000x reference)
//
#include <hip/hip_runtime.h>
#include <math.h>

#define T_LEN 100
#define K_LEN 25
#define DLAT 64
#define DHID 128
#define CST 68
#define AST 68

// ---------------------------------------------------------------------------
// buildW: collapse Conv1d(1,64,25,pad=12) + Linear(100,1) into one matrix:
//   h2[n,c] = sum_i x[n,i] * W[c,i] + b2[c]
// Also re-zeroes the last-block-done counter (graph replay safe: runs first).
// ---------------------------------------------------------------------------
__global__ __launch_bounds__(256) void buildW(const float* __restrict__ conv_w,
                                              const float* __restrict__ conv_b,
                                              const float* __restrict__ fc1_w,
                                              const float* __restrict__ fc1_b,
                                              float* __restrict__ W,
                                              float* __restrict__ b2,
                                              unsigned* __restrict__ bar) {
    int idx = blockIdx.x * 256 + threadIdx.x;
    if (idx < 64 * T_LEN) {
        int c = idx / T_LEN, i = idx % T_LEN;
        int t0 = i - 12 > 0 ? i - 12 : 0;
        int t1 = i + 12 < T_LEN - 1 ? i + 12 : T_LEN - 1;
        float acc = 0.f;
        for (int t = t0; t <= t1; ++t)
            acc += fc1_w[t] * conv_w[c * K_LEN + (i - t + 12)];
        W[idx] = acc;
    } else if (idx < 64 * T_LEN + 64) {
        int c = idx - 64 * T_LEN;
        float S = 0.f;
        for (int t = 0; t < T_LEN; ++t) S += fc1_w[t];
        b2[c] = conv_b[c] * S + fc1_b[0];
    } else if (idx == 64 * T_LEN + 64) {
        bar[0] = 0u;
    }
}

// ---------------------------------------------------------------------------
// phaseCF6T: r13's phaseCF6 hot phases UNCHANGED (fastest measured, 87us;
// its 44MB spill is proven free: r9's no-spill variant ran 200us, r11/r13
// spill-shrink attempts were null). ADDITIVE last-block-done tail (r5-proven
// pattern: atomic counter, no block waits -> no residency requirement)
// runs BN-stats (D) + head (E) in the last block, removing 2 launches
// (~40us of the ~80us inter-launch gap).
// ---------------------------------------------------------------------------
__global__ __launch_bounds__(512, 4) void phaseCF6T(const float* __restrict__ x,
                                                    const int* __restrict__ ei,
                                                    const float* __restrict__ Wm,
                                                    const float* __restrict__ b2,
                                                    const float* __restrict__ rel_w,
                                                    const float* __restrict__ rel_b,
                                                    const float* __restrict__ root_w,
                                                    const float* __restrict__ gamma,
                                                    const float* __restrict__ beta,
                                                    const float* __restrict__ fc2_w,
                                                    const float* __restrict__ fc2_b,
                                                    float* __restrict__ Sg,
                                                    float* __restrict__ Qg,
                                                    float* __restrict__ y,
                                                    unsigned* __restrict__ bar,
                                                    int E, int G, int N) {
    __shared__ float h2s[64 * CST];
    __shared__ float aggs[64 * CST];
    __shared__ unsigned Asu[64 * AST];

    int tid = threadIdx.x;
    int bid = blockIdx.x;
    int lane = tid & 63;
    int w = __builtin_amdgcn_readfirstlane(tid >> 6);  // 0..7, uniform

    // bijective XCD swizzle (m204): graphs sharing edge cachelines land on
    // the same XCD so the stride-G edge reads are L2 hits.
    int q = G >> 3, r = G & 7;
    int xc = bid & 7, o = bid >> 3;
    int g = (xc < r ? xc * (q + 1) : r * (q + 1) + (xc - r) * q) + o;

    int epg = E / G;
    bool fast = (epg == 2048);

    // 0. issue strided edge loads EARLY; the vmcnt wait lands after the
    // encoder loop, so HBM/L2 latency hides under phase 1 compute.
    int es0 = 0, es1 = 0, es2 = 0, es3 = 0;
    int ed0 = 0, ed1 = 0, ed2 = 0, ed3 = 0;
    if (fast) {
        int e0 = g + tid * G;
        int st = 512 * G;
        es0 = ei[e0];            ed0 = ei[E + e0];
        es1 = ei[e0 + st];       ed1 = ei[E + e0 + st];
        es2 = ei[e0 + 2 * st];   ed2 = ei[E + e0 + 2 * st];
        es3 = ei[e0 + 3 * st];   ed3 = ei[E + e0 + 3 * st];
    }

    // zero adjacency counters
    for (int idx = tid; idx < 64 * AST; idx += 512) Asu[idx] = 0u;

    // 1. encoder: h2s[lane][8w..8w+8)  (rolled tq loop, r13 form)
    {
        const float4* __restrict__ xp =
            (const float4*)(x + (size_t)(g * 64 + lane) * T_LEN);
        const float* __restrict__ Wb = Wm + w * 8 * T_LEN;  // uniform
        float acc[8];
#pragma unroll
        for (int c = 0; c < 8; ++c) acc[c] = 0.f;
        for (int tq = 0; tq < T_LEN / 4; ++tq) {
            float4 xv = xp[tq];
#pragma unroll
            for (int c = 0; c < 8; ++c) {
                const float* wr = Wb + c * T_LEN + tq * 4;  // uniform -> s_load
                acc[c] += xv.x * wr[0] + xv.y * wr[1] + xv.z * wr[2] + xv.w * wr[3];
            }
        }
        float4 o0, o1;
        o0.x = acc[0] + b2[w * 8 + 0];
        o0.y = acc[1] + b2[w * 8 + 1];
        o0.z = acc[2] + b2[w * 8 + 2];
        o0.w = acc[3] + b2[w * 8 + 3];
        o1.x = acc[4] + b2[w * 8 + 4];
        o1.y = acc[5] + b2[w * 8 + 5];
        o1.z = acc[6] + b2[w * 8 + 6];
        o1.w = acc[7] + b2[w * 8 + 7];
        *(float4*)&h2s[lane * CST + w * 8] = o0;
        *(float4*)&h2s[lane * CST + w * 8 + 4] = o1;
    }
    __syncthreads();

    // 2. edge counting via LDS atomics
    if (fast) {
        atomicAdd(&Asu[(ed0 & 63) * AST + (es0 & 63)], 1u);
        atomicAdd(&Asu[(ed1 & 63) * AST + (es1 & 63)], 1u);
        atomicAdd(&Asu[(ed2 & 63) * AST + (es2 & 63)], 1u);
        atomicAdd(&Asu[(ed3 & 63) * AST + (es3 & 63)], 1u);
    } else {
        for (int k = tid; k < epg; k += 512) {
            int e = g + k * G;
            atomicAdd(&Asu[(ei[E + e] & 63) * AST + (ei[e] & 63)], 1u);
        }
    }
    __syncthreads();

    // 3. agg = A @ h2 (convert counts inline). thread owns (n, n+32) x 4 ch.
    {
        int c4 = (tid & 15) * 4;
        int n0 = tid >> 4;  // 0..31
#pragma unroll
        for (int i = 0; i < 2; ++i) {
            int n = n0 + 32 * i;
            float4 a4 = {0.f, 0.f, 0.f, 0.f};
#pragma unroll 4
            for (int s4 = 0; s4 < 16; ++s4) {
                uint4 au = *(const uint4*)&Asu[n * AST + 4 * s4];
                float a0 = (float)au.x, a1 = (float)au.y;
                float a2 = (float)au.z, a3 = (float)au.w;
                float4 h0 = *(const float4*)&h2s[(4 * s4 + 0) * CST + c4];
                float4 h1 = *(const float4*)&h2s[(4 * s4 + 1) * CST + c4];
                float4 h2v = *(const float4*)&h2s[(4 * s4 + 2) * CST + c4];
                float4 h3 = *(const float4*)&h2s[(4 * s4 + 3) * CST + c4];
                a4.x += a0 * h0.x + a1 * h1.x + a2 * h2v.x + a3 * h3.x;
                a4.y += a0 * h0.y + a1 * h1.y + a2 * h2v.y + a3 * h3.y;
                a4.z += a0 * h0.z + a1 * h1.z + a2 * h2v.z + a3 * h3.z;
                a4.w += a0 * h0.w + a1 * h1.w + a2 * h2v.w + a3 * h3.w;
            }
            *(float4*)&aggs[n * CST + c4] = a4;
        }
    }
    __syncthreads();

    // 4. part2: wave w owns j in [16w,16w+16), jb halves of 8 j's,
    //    channel chunks of 8 floats (16 live z floats + acc[8]).
#pragma unroll
    for (int jb = 0; jb < 2; ++jb) {
        float acc[8];
#pragma unroll
        for (int ji = 0; ji < 8; ++ji) acc[ji] = 0.f;

#pragma unroll
        for (int mc = 0; mc < 8; ++mc) {
            float4 za0 = *(const float4*)&aggs[lane * CST + mc * 8];
            float4 za1 = *(const float4*)&aggs[lane * CST + mc * 8 + 4];
            float4 zh0 = *(const float4*)&h2s[lane * CST + mc * 8];
            float4 zh1 = *(const float4*)&h2s[lane * CST + mc * 8 + 4];
#pragma unroll
            for (int ji = 0; ji < 8; ++ji) {
                int j = w * 16 + jb * 8 + ji;  // uniform
                const float* rp = rel_w + (size_t)j * DLAT + mc * 8;   // 32B run
                const float* op = root_w + (size_t)j * DLAT + mc * 8;
                float a = acc[ji];
                a += za0.x * rp[0] + za0.y * rp[1] + za0.z * rp[2] + za0.w * rp[3];
                a += za1.x * rp[4] + za1.y * rp[5] + za1.z * rp[6] + za1.w * rp[7];
                a += zh0.x * op[0] + zh0.y * op[1] + zh0.z * op[2] + zh0.w * op[3];
                a += zh1.x * op[4] + zh1.y * op[5] + zh1.z * op[6] + zh1.w * op[7];
                acc[ji] = a;
            }
        }

#pragma unroll
        for (int ji = 0; ji < 8; ++ji) {
            int j = w * 16 + jb * 8 + ji;
            float outv = acc[ji] + rel_b[j];
            float sq = outv * outv;
#pragma unroll
            for (int off = 32; off; off >>= 1) {
                outv += __shfl_xor(outv, off);
                sq += __shfl_xor(sq, off);
            }
            if (lane == 0) {
                Sg[(size_t)g * DHID + j] = outv;
                Qg[(size_t)g * DHID + j] = sq;
            }
        }
    }

    // ======================= last-block-done tail (D + E) ===================
    // No block ever waits: the last block to arrive does the tail. r5-proven
    // fence/atomic pattern; works regardless of residency.
    int* flag = (int*)Asu;  // Asu dead after part3
    __syncthreads();        // all Sg/Qg stores issued & drained (barrier semantics)
    if (tid == 0) {
        __threadfence();    // release this block's Sg/Qg device-wide
        unsigned old = __hip_atomic_fetch_add(&bar[0], 1u, __ATOMIC_ACQ_REL,
                                              __HIP_MEMORY_SCOPE_AGENT);
        *flag = (old == (unsigned)gridDim.x - 1u) ? 1 : 0;
        if (*flag) __threadfence();  // acquire all other blocks' writes
    }
    __syncthreads();
    if (!*flag) return;

    // D: BN stats. 4-way graph split per channel; coalesced Sg/Qg reads.
    float* SD = h2s;           // 512 f
    float* QD = h2s + 512;     // 512 f
    float* abL = h2s + 1024;   // 256 f
    {
        int j = tid & 127, gq = tid >> 7;
        float s = 0.f, qv = 0.f;
        for (int gi = gq; gi < G; gi += 4) {
            s += Sg[(size_t)gi * DHID + j];
            qv += Qg[(size_t)gi * DHID + j];
        }
        SD[gq * DHID + j] = s;
        QD[gq * DHID + j] = qv;
    }
    __syncthreads();
    if (tid < DHID) {
        float S = SD[tid] + SD[DHID + tid] + SD[2 * DHID + tid] + SD[3 * DHID + tid];
        float Q = QD[tid] + QD[DHID + tid] + QD[2 * DHID + tid] + QD[3 * DHID + tid];
        float inv_n = 1.f / (float)N;
        float mean = S * inv_n;
        float var = Q * inv_n - mean * mean;
        float a = rsqrtf(var + 1e-5f) * gamma[tid];
        float b = beta[tid] - mean * a;
        abL[tid] = a;
        abL[DHID + tid] = b;
    }
    __syncthreads();

    // E: one wave per graph; lane covers j=lane and j=lane+64.
    {
        float fb0 = fc2_b[0], fb1 = fc2_b[1], fb2 = fc2_b[2];
        for (int gg = w; gg < G; gg += 8) {
            float S0 = Sg[(size_t)gg * DHID + lane];
            float Q0 = Qg[(size_t)gg * DHID + lane];
            float S1 = Sg[(size_t)gg * DHID + 64 + lane];
            float Q1 = Qg[(size_t)gg * DHID + 64 + lane];
            float a0 = abL[lane], b0 = abL[DHID + lane];
            float a1 = abL[64 + lane], b1 = abL[DHID + 64 + lane];
            float p0 = (a0 * a0 * Q0 + 2.f * a0 * b0 * S0) * (1.f / 64.f) + b0 * b0;
            float p1 = (a1 * a1 * Q1 + 2.f * a1 * b1 * S1) * (1.f / 64.f) + b1 * b1;
            float l0 = logf(fmaxf(p0, 1e-6f));
            float l1 = logf(fmaxf(p1, 1e-6f));
            float v0 = l0 * fc2_w[lane] + l1 * fc2_w[64 + lane];
            float v1 = l0 * fc2_w[DHID + lane] + l1 * fc2_w[DHID + 64 + lane];
            float v2 = l0 * fc2_w[2 * DHID + lane] + l1 * fc2_w[2 * DHID + 64 + lane];
#pragma unroll
            for (int off = 32; off; off >>= 1) {
                v0 += __shfl_xor(v0, off);
                v1 += __shfl_xor(v1, off);
                v2 += __shfl_xor(v2, off);
            }
            if (lane == 0) {
                y[(size_t)gg * 3 + 0] = 1.f / (1.f + expf(-(v0 + fb0)));
                y[(size_t)gg * 3 + 1] = 1.f / (1.f + expf(-(v1 + fb1)));
                y[(size_t)gg * 3 + 2] = 1.f / (1.f + expf(-(v2 + fb2)));
            }
        }
    }
}

// ---------------------------------------------------------------------------
extern "C" void kernel_launch(void* const* d_in, const int* in_sizes, int n_in,
                              void* d_out, int out_size, void* d_ws, size_t ws_size,
                              hipStream_t stream) {
    const float* x      = (const float*)d_in[0];
    const int*   ei     = (const int*)d_in[1];
    const float* conv_w = (const float*)d_in[3];
    const float* conv_b = (const float*)d_in[4];
    const float* fc1_w  = (const float*)d_in[5];
    const float* fc1_b  = (const float*)d_in[6];
    const float* rel_w  = (const float*)d_in[7];
    const float* rel_b  = (const float*)d_in[8];
    const float* root_w = (const float*)d_in[9];
    const float* gamma  = (const float*)d_in[10];
    const float* beta   = (const float*)d_in[11];
    const float* fc2_w  = (const float*)d_in[12];
    const float* fc2_b  = (const float*)d_in[13];
    float* y = (float*)d_out;

    int N = in_sizes[2];       // 32768
    int E = in_sizes[1] / 2;   // 1048576
    int G = N / 64;            // 512

    float* Sg     = (float*)d_ws;                  // G*128
    float* Qg     = Sg + (size_t)G * DHID;         // G*128
    float* Wm     = Qg + (size_t)G * DHID;         // 64*100
    float* b2     = Wm + 64 * T_LEN;               // 64
    unsigned* bar = (unsigned*)(b2 + 64);          // 1 (padded)

    buildW<<<26, 256, 0, stream>>>(conv_w, conv_b, fc1_w, fc1_b, Wm, b2, bar);
    phaseCF6T<<<G, 512, 0, stream>>>(x, ei, Wm, b2, rel_w, rel_b, root_w,
                                     gamma, beta, fc2_w, fc2_b,
                                     Sg, Qg, y, bar, E, G, N);
}

// Round 15
// 124.036 us; speedup vs baseline: 2.1557x; 2.1557x over previous
//
#include <hip/hip_runtime.h>
#include <math.h>

#define T_LEN 100
#define K_LEN 25
#define DLAT 64
#define DHID 128
#define CST 68
#define AST 68
#define ZST 136   // zb row stride in shorts (bf16); 272B, 16B-aligned

typedef __attribute__((ext_vector_type(8))) short bf16x8;
typedef __attribute__((ext_vector_type(4))) float f32x4v;

union ABu { bf16x8 v; unsigned u[4]; uint2 t[2]; };

// pack 2 f32 -> 2 bf16 (RNE) in one u32 (no builtin on gfx950; T12 recipe)
__device__ __forceinline__ unsigned pk(float lo, float hi) {
    unsigned r;
    asm("v_cvt_pk_bf16_f32 %0, %1, %2" : "=v"(r) : "v"(lo), "v"(hi));
    return r;
}

// ---------------------------------------------------------------------------
// buildW: collapse Conv1d(1,64,25,pad=12) + Linear(100,1) into one matrix.
// ---------------------------------------------------------------------------
__global__ __launch_bounds__(256) void buildW(const float* __restrict__ conv_w,
                                              const float* __restrict__ conv_b,
                                              const float* __restrict__ fc1_w,
                                              const float* __restrict__ fc1_b,
                                              float* __restrict__ W,
                                              float* __restrict__ b2) {
    int idx = blockIdx.x * 256 + threadIdx.x;
    if (idx < 64 * T_LEN) {
        int c = idx / T_LEN, i = idx % T_LEN;
        int t0 = i - 12 > 0 ? i - 12 : 0;
        int t1 = i + 12 < T_LEN - 1 ? i + 12 : T_LEN - 1;
        float acc = 0.f;
        for (int t = t0; t <= t1; ++t)
            acc += fc1_w[t] * conv_w[c * K_LEN + (i - t + 12)];
        W[idx] = acc;
    } else if (idx < 64 * T_LEN + 64) {
        int c = idx - 64 * T_LEN;
        float S = 0.f;
        for (int t = 0; t < T_LEN; ++t) S += fc1_w[t];
        b2[c] = conv_b[c] * S + fc1_b[0];
    }
}

// ---------------------------------------------------------------------------
// phaseCF7: r13 champion with part2 replaced by bf16 MFMA (16x16x32).
// Z = [agg | h2] kept as a bf16 LDS copy zb[64][136] (packed incrementally:
// encoder packs h2, agg packs its output; fp32 aggs array DELETED -> LDS
// total unchanged at 52224B, 2 blocks/CU).
// Per wave: j-block 16w..16w+16; D[64x16] via 4 M-tiles x 4 K-steps = 16
// MFMA. K-order of A/B fragments uses one consistent (lane,e)->k map, so
// any HW k-permutation cancels; outer maps: A lane&15=M-row, B lane&15=N-col;
// C/D col=lane&15, row=(lane>>4)*4+reg [measured m89/91].
// ---------------------------------------------------------------------------
__global__ __launch_bounds__(512, 4) void phaseCF7(const float* __restrict__ x,
                                                   const int* __restrict__ ei,
                                                   const float* __restrict__ Wm,
                                                   const float* __restrict__ b2,
                                                   const float* __restrict__ rel_w,
                                                   const float* __restrict__ rel_b,
                                                   const float* __restrict__ root_w,
                                                   float* __restrict__ Sg,
                                                   float* __restrict__ Qg,
                                                   int E, int G) {
    __shared__ float h2s[64 * CST];
    __shared__ unsigned Asu[64 * AST];
    __shared__ unsigned short zb[64 * ZST];   // bf16 Z = [agg(0..64) | h2(64..128)]

    int tid = threadIdx.x;
    int bid = blockIdx.x;
    int lane = tid & 63;
    int w = __builtin_amdgcn_readfirstlane(tid >> 6);  // 0..7, uniform

    // bijective XCD swizzle (m204)
    int q = G >> 3, r = G & 7;
    int xc = bid & 7, o = bid >> 3;
    int g = (xc < r ? xc * (q + 1) : r * (q + 1) + (xc - r) * q) + o;

    int epg = E / G;
    bool fast = (epg == 2048);

    // 0. issue strided edge loads EARLY (drain after encoder)
    int es0 = 0, es1 = 0, es2 = 0, es3 = 0;
    int ed0 = 0, ed1 = 0, ed2 = 0, ed3 = 0;
    if (fast) {
        int e0 = g + tid * G;
        int st = 512 * G;
        es0 = ei[e0];            ed0 = ei[E + e0];
        es1 = ei[e0 + st];       ed1 = ei[E + e0 + st];
        es2 = ei[e0 + 2 * st];   ed2 = ei[E + e0 + 2 * st];
        es3 = ei[e0 + 3 * st];   ed3 = ei[E + e0 + 3 * st];
    }

    // zero adjacency counters
    for (int idx = tid; idx < 64 * AST; idx += 512) Asu[idx] = 0u;

    // 1. encoder: h2s[lane][8w..8w+8) fp32 + bf16 copy into zb[lane][64+8w..]
    {
        const float4* __restrict__ xp =
            (const float4*)(x + (size_t)(g * 64 + lane) * T_LEN);
        const float* __restrict__ Wb = Wm + w * 8 * T_LEN;  // uniform -> s_load
        float acc[8];
#pragma unroll
        for (int c = 0; c < 8; ++c) acc[c] = 0.f;
        for (int tq = 0; tq < T_LEN / 4; ++tq) {
            float4 xv = xp[tq];
#pragma unroll
            for (int c = 0; c < 8; ++c) {
                const float* wr = Wb + c * T_LEN + tq * 4;
                acc[c] += xv.x * wr[0] + xv.y * wr[1] + xv.z * wr[2] + xv.w * wr[3];
            }
        }
        float4 o0, o1;
        o0.x = acc[0] + b2[w * 8 + 0];
        o0.y = acc[1] + b2[w * 8 + 1];
        o0.z = acc[2] + b2[w * 8 + 2];
        o0.w = acc[3] + b2[w * 8 + 3];
        o1.x = acc[4] + b2[w * 8 + 4];
        o1.y = acc[5] + b2[w * 8 + 5];
        o1.z = acc[6] + b2[w * 8 + 6];
        o1.w = acc[7] + b2[w * 8 + 7];
        *(float4*)&h2s[lane * CST + w * 8] = o0;
        *(float4*)&h2s[lane * CST + w * 8 + 4] = o1;
        uint4 uv = {pk(o0.x, o0.y), pk(o0.z, o0.w), pk(o1.x, o1.y), pk(o1.z, o1.w)};
        *(uint4*)&zb[lane * ZST + 64 + w * 8] = uv;
    }
    __syncthreads();

    // 2. edge counting via LDS atomics
    if (fast) {
        atomicAdd(&Asu[(ed0 & 63) * AST + (es0 & 63)], 1u);
        atomicAdd(&Asu[(ed1 & 63) * AST + (es1 & 63)], 1u);
        atomicAdd(&Asu[(ed2 & 63) * AST + (es2 & 63)], 1u);
        atomicAdd(&Asu[(ed3 & 63) * AST + (es3 & 63)], 1u);
    } else {
        for (int k = tid; k < epg; k += 512) {
            int e = g + k * G;
            atomicAdd(&Asu[(ei[E + e] & 63) * AST + (ei[e] & 63)], 1u);
        }
    }
    __syncthreads();

    // 3. agg = A @ h2 (counts inline); result packed bf16 into zb[n][0..64)
    {
        int c4 = (tid & 15) * 4;
        int n0 = tid >> 4;  // 0..31
#pragma unroll
        for (int i = 0; i < 2; ++i) {
            int n = n0 + 32 * i;
            float4 a4 = {0.f, 0.f, 0.f, 0.f};
#pragma unroll 4
            for (int s4 = 0; s4 < 16; ++s4) {
                uint4 au = *(const uint4*)&Asu[n * AST + 4 * s4];
                float a0 = (float)au.x, a1 = (float)au.y;
                float a2 = (float)au.z, a3 = (float)au.w;
                float4 h0 = *(const float4*)&h2s[(4 * s4 + 0) * CST + c4];
                float4 h1 = *(const float4*)&h2s[(4 * s4 + 1) * CST + c4];
                float4 h2v = *(const float4*)&h2s[(4 * s4 + 2) * CST + c4];
                float4 h3 = *(const float4*)&h2s[(4 * s4 + 3) * CST + c4];
                a4.x += a0 * h0.x + a1 * h1.x + a2 * h2v.x + a3 * h3.x;
                a4.y += a0 * h0.y + a1 * h1.y + a2 * h2v.y + a3 * h3.y;
                a4.z += a0 * h0.z + a1 * h1.z + a2 * h2v.z + a3 * h3.z;
                a4.w += a0 * h0.w + a1 * h1.w + a2 * h2v.w + a3 * h3.w;
            }
            uint2 uv = {pk(a4.x, a4.y), pk(a4.z, a4.w)};
            *(uint2*)&zb[n * ZST + c4] = uv;
        }
    }
    __syncthreads();

    // 4. part2 via MFMA: out[64,128] = Z[64,128] @ W2[128,128]^T per graph.
    //    Wave w: j in [16w,16w+16). 4 M-tiles x 4 K-steps, B preloaded.
    {
        const int l15 = lane & 15, lg = lane >> 4;
        const int j = w * 16 + l15;

        ABu B[4];
#pragma unroll
        for (int kk = 0; kk < 4; ++kk) {
            const float* src = (kk < 2)
                ? (rel_w + (size_t)j * DLAT + kk * 32)
                : (root_w + (size_t)j * DLAT + (kk - 2) * 32);
            float4 f0 = *(const float4*)(src + lg * 4);
            float4 f1 = *(const float4*)(src + lg * 4 + 16);
            B[kk].u[0] = pk(f0.x, f0.y);
            B[kk].u[1] = pk(f0.z, f0.w);
            B[kk].u[2] = pk(f1.x, f1.y);
            B[kk].u[3] = pk(f1.z, f1.w);
        }

        f32x4v d0 = {0.f, 0.f, 0.f, 0.f};
        f32x4v d1 = d0, d2 = d0, d3 = d0;
#pragma unroll
        for (int kk = 0; kk < 4; ++kk) {
            int cb = kk * 32 + lg * 4;   // shorts; same k-map as B (cancels)
            ABu a0_, a1_, a2_, a3_;
            a0_.t[0] = *(const uint2*)&zb[(0 * 16 + l15) * ZST + cb];
            a0_.t[1] = *(const uint2*)&zb[(0 * 16 + l15) * ZST + cb + 16];
            a1_.t[0] = *(const uint2*)&zb[(1 * 16 + l15) * ZST + cb];
            a1_.t[1] = *(const uint2*)&zb[(1 * 16 + l15) * ZST + cb + 16];
            a2_.t[0] = *(const uint2*)&zb[(2 * 16 + l15) * ZST + cb];
            a2_.t[1] = *(const uint2*)&zb[(2 * 16 + l15) * ZST + cb + 16];
            a3_.t[0] = *(const uint2*)&zb[(3 * 16 + l15) * ZST + cb];
            a3_.t[1] = *(const uint2*)&zb[(3 * 16 + l15) * ZST + cb + 16];
            d0 = __builtin_amdgcn_mfma_f32_16x16x32_bf16(a0_.v, B[kk].v, d0, 0, 0, 0);
            d1 = __builtin_amdgcn_mfma_f32_16x16x32_bf16(a1_.v, B[kk].v, d1, 0, 0, 0);
            d2 = __builtin_amdgcn_mfma_f32_16x16x32_bf16(a2_.v, B[kk].v, d2, 0, 0, 0);
            d3 = __builtin_amdgcn_mfma_f32_16x16x32_bf16(a3_.v, B[kk].v, d3, 0, 0, 0);
        }

        // moments: each lane holds 16 out-values for its j (4 rows x 4 tiles)
        float rb = rel_b[j];
        float s = 0.f, qm = 0.f;
#pragma unroll
        for (int e = 0; e < 4; ++e) { float ov = d0[e] + rb; s += ov; qm += ov * ov; }
#pragma unroll
        for (int e = 0; e < 4; ++e) { float ov = d1[e] + rb; s += ov; qm += ov * ov; }
#pragma unroll
        for (int e = 0; e < 4; ++e) { float ov = d2[e] + rb; s += ov; qm += ov * ov; }
#pragma unroll
        for (int e = 0; e < 4; ++e) { float ov = d3[e] + rb; s += ov; qm += ov * ov; }
        s += __shfl_xor(s, 16);  qm += __shfl_xor(qm, 16);
        s += __shfl_xor(s, 32);  qm += __shfl_xor(qm, 32);
        if (lg == 0) {
            Sg[(size_t)g * DHID + j] = s;
            Qg[(size_t)g * DHID + j] = qm;
        }
    }
}

// ---------------------------------------------------------------------------
// Phase D: BN stats per channel -> a[j], b[j] (scale/shift)
// ---------------------------------------------------------------------------
__global__ __launch_bounds__(256) void phaseD2(const float* __restrict__ Sg,
                                               const float* __restrict__ Qg,
                                               const float* __restrict__ gamma,
                                               const float* __restrict__ beta,
                                               float* __restrict__ ab,
                                               int G, int N) {
    int j = blockIdx.x;
    int t = threadIdx.x;
    float s = 0.f, q = 0.f;
    for (int g = t; g < G; g += 256) {
        s += Sg[g * DHID + j];
        q += Qg[g * DHID + j];
    }
#pragma unroll
    for (int off = 32; off; off >>= 1) {
        s += __shfl_xor(s, off);
        q += __shfl_xor(q, off);
    }
    __shared__ float rs[4], rq[4];
    int wv = t >> 6;
    if ((t & 63) == 0) { rs[wv] = s; rq[wv] = q; }
    __syncthreads();
    if (t == 0) {
        s = rs[0] + rs[1] + rs[2] + rs[3];
        q = rq[0] + rq[1] + rq[2] + rq[3];
        float inv_n = 1.f / (float)N;
        float mean = s * inv_n;
        float var = q * inv_n - mean * mean;
        float a = rsqrtf(var + 1e-5f) * gamma[j];
        float b = beta[j] - mean * a;
        ab[j] = a;
        ab[DHID + j] = b;
    }
}

// ---------------------------------------------------------------------------
// Phase E: pooled = (a^2 Q + 2ab S)/64 + b^2 ; log(clamp) ; fc2 ; sigmoid
// ---------------------------------------------------------------------------
__global__ __launch_bounds__(128) void phaseE(const float* __restrict__ Sg,
                                              const float* __restrict__ Qg,
                                              const float* __restrict__ ab,
                                              const float* __restrict__ fc2_w,
                                              const float* __restrict__ fc2_b,
                                              float* __restrict__ y) {
    int g = blockIdx.x;
    int j = threadIdx.x;
    __shared__ float ps[DHID];
    float a = ab[j], b = ab[DHID + j];
    float S = Sg[g * DHID + j], Q = Qg[g * DHID + j];
    float pooled = (a * a * Q + 2.f * a * b * S) * (1.f / 64.f) + b * b;
    pooled = fmaxf(pooled, 1e-6f);
    ps[j] = logf(pooled);
    __syncthreads();
    if (j < 3) {
        float acc = fc2_b[j];
        for (int c = 0; c < DHID; ++c) acc += ps[c] * fc2_w[j * DHID + c];
        y[g * 3 + j] = 1.f / (1.f + expf(-acc));
    }
}

// ---------------------------------------------------------------------------
extern "C" void kernel_launch(void* const* d_in, const int* in_sizes, int n_in,
                              void* d_out, int out_size, void* d_ws, size_t ws_size,
                              hipStream_t stream) {
    const float* x      = (const float*)d_in[0];
    const int*   ei     = (const int*)d_in[1];
    const float* conv_w = (const float*)d_in[3];
    const float* conv_b = (const float*)d_in[4];
    const float* fc1_w  = (const float*)d_in[5];
    const float* fc1_b  = (const float*)d_in[6];
    const float* rel_w  = (const float*)d_in[7];
    const float* rel_b  = (const float*)d_in[8];
    const float* root_w = (const float*)d_in[9];
    const float* gamma  = (const float*)d_in[10];
    const float* beta   = (const float*)d_in[11];
    const float* fc2_w  = (const float*)d_in[12];
    const float* fc2_b  = (const float*)d_in[13];
    float* y = (float*)d_out;

    int N = in_sizes[2];       // 32768
    int E = in_sizes[1] / 2;   // 1048576
    int G = N / 64;            // 512

    float* Sg = (float*)d_ws;                  // G*128
    float* Qg = Sg + (size_t)G * DHID;         // G*128
    float* ab = Qg + (size_t)G * DHID;         // 2*128
    float* Wm = ab + 2 * DHID;                 // 64*100
    float* b2 = Wm + 64 * T_LEN;               // 64

    buildW<<<26, 256, 0, stream>>>(conv_w, conv_b, fc1_w, fc1_b, Wm, b2);
    phaseCF7<<<G, 512, 0, stream>>>(x, ei, Wm, b2, rel_w, rel_b, root_w,
                                    Sg, Qg, E, G);
    phaseD2<<<DHID, 256, 0, stream>>>(Sg, Qg, gamma, beta, ab, G, N);
    phaseE<<<G, DHID, 0, stream>>>(Sg, Qg, ab, fc2_w, fc2_b, y);
}